// Round 1
// baseline (776.049 us; speedup 1.0000x reference)
//
#include <hip/hip_runtime.h>
#include <math.h>

// Problem constants (from reference)
#define N_NODES 50000
#define N_EDGES 800000
#define IN_DIM  192      // 2*O + ED
#define BN_EPS  1e-5f

// Workspace layout (4-byte word offsets):
//   P1p    [N,64]  uint @ 0          packed bf16x2 {chan n, chan n+64} of n_feat@W1^T
//   P2p    [N,64]  uint @ 3,200,000  same for W2^T
//   agg    [N,64]  f32  @ 6,400,000
//   stats1 [256]   f32  @ 9,600,000  (sum[128], sumsq[128])
//   ss1    [256]   f32  @ +256       (scale[128], shift[128])
//   stats2 [128]   f32  @ +512
//   ss2    [128]   f32  @ +640
//   hbuf   [E,64]  uint @ 9,601,024  packed bf16x2 {filt,core} per chan
//   perm   [E]     uint @ OFF_PERM   edge ids sorted by dst (counting sort)
//   offs   [N+1]   uint @ OFF_OFFS   CSR row offsets per dst node
//   deg    [N]     uint @ OFF_DEG    histogram scratch
//   cursor [N]     uint @ OFF_CURS   scatter cursors (copy of offs)
#define OFF_P2P    3200000
#define OFF_AGG    6400000
#define OFF_STATS1 9600000
#define OFF_HBUF   9601024
#define WS_WORDS_NEEDED (OFF_HBUF + (size_t)N_EDGES * 64)
#define OFF_PERM   (OFF_HBUF + (size_t)N_EDGES * 64)
#define OFF_OFFS   (OFF_PERM + N_EDGES)
#define OFF_DEG    (OFF_OFFS + N_NODES + 1)
#define OFF_CURS   (OFF_DEG + N_NODES)
#define WS_WORDS_SORTED (OFF_CURS + N_NODES)

typedef __bf16 bf16x8 __attribute__((ext_vector_type(8)));
typedef __bf16 bf16x2 __attribute__((ext_vector_type(2)));
typedef float  f32x4  __attribute__((ext_vector_type(4)));

__device__ __forceinline__ unsigned pack_bf16x2(float lo, float hi) {
  union { bf16x2 v; unsigned u; } pk;
  pk.v[0] = (__bf16)lo; pk.v[1] = (__bf16)hi;
  return pk.u;
}
// fast transcendentals (native v_exp/v_log/v_rcp)
__device__ __forceinline__ float fast_sigmoid(float f) {
  return __builtin_amdgcn_rcpf(1.f + __expf(-f));
}
__device__ __forceinline__ float fast_softplus(float g) {
  return fmaxf(g, 0.f) + __logf(1.f + __expf(-fabsf(g)));
}

// ---------------------------------------------------------------------------
// Kernel 1: P1p[n][o] = pack(bf16(n_feat[n]·W[o][0:64]), bf16(n_feat[n]·W[o+64][0:64]))
//           P2p same with k-range 64:128.
// 256 threads = 64 chans (o) x 4 roles (sel): {P1 lo, P1 hi, P2 lo, P2 hi}.
__global__ __launch_bounds__(256) void k_precompute(
    const float* __restrict__ n_feat, const float* __restrict__ W,
    unsigned* __restrict__ P1p, unsigned* __restrict__ P2p) {
  const int tid = threadIdx.x;
  const int o   = tid & 63;
  const int sel = tid >> 6;                 // 0..3
  const int ch  = o + (sel & 1) * 64;
  const int kb  = (sel & 2) ? 64 : 0;
  float4 wreg[16];
  const float* wrow = W + (size_t)ch * IN_DIM + kb;
#pragma unroll
  for (int i = 0; i < 16; ++i) wreg[i] = *(const float4*)(wrow + i * 4);
  __shared__ float xrow[4][64];
  __shared__ float accbuf[4][4][64];        // [sel][r][o]
  for (int r0 = blockIdx.x * 4; r0 < N_NODES; r0 += gridDim.x * 4) {
    xrow[tid >> 6][tid & 63] = n_feat[(size_t)(r0 + (tid >> 6)) * 64 + (tid & 63)];
    __syncthreads();
    float acc[4] = {0.f, 0.f, 0.f, 0.f};
#pragma unroll
    for (int kk = 0; kk < 16; ++kk) {
      float4 wv = wreg[kk];
#pragma unroll
      for (int r = 0; r < 4; ++r) {
        float4 xv = *(const float4*)&xrow[r][kk * 4];
        acc[r] += wv.x * xv.x + wv.y * xv.y + wv.z * xv.z + wv.w * xv.w;
      }
    }
#pragma unroll
    for (int r = 0; r < 4; ++r) accbuf[sel][r][o] = acc[r];
    __syncthreads();
    // thread (o, sel) packs+writes node row r0+sel
    const size_t rr = (size_t)(r0 + sel) * 64 + o;
    P1p[rr] = pack_bf16x2(accbuf[0][sel][o], accbuf[1][sel][o]);
    P2p[rr] = pack_bf16x2(accbuf[2][sel][o], accbuf[3][sel][o]);
    __syncthreads();
  }
}

// ---------------------------------------------------------------------------
// MFMA edge-pass core.  Wave computes h[16 edges][128 ch] for group base e0.
//   Q = e_feat_tile(bf16) @ W3^T(bf16) via 16x16x32 MFMA, f32 accumulate.
//   D-frag: lane holds D[m=(lane>>4)*4+r][n=nt*16+(lane&15)]
__device__ __forceinline__ void load_W3_frags(const float* __restrict__ W,
                                              int lane, bf16x8* Bf) {
  const int c = lane & 15, q = lane >> 4;
#pragma unroll
  for (int nt = 0; nt < 8; ++nt) {
#pragma unroll
    for (int ks = 0; ks < 2; ++ks) {
      const float* wr = W + (size_t)(nt * 16 + c) * IN_DIM + 128 + ks * 32 + q * 8;
      f32x4 w0 = *(const f32x4*)wr;
      f32x4 w1 = *(const f32x4*)(wr + 4);
      bf16x8 f;
#pragma unroll
      for (int j = 0; j < 4; ++j) { f[j] = (__bf16)w0[j]; f[4 + j] = (__bf16)w1[j]; }
      Bf[nt * 2 + ks] = f;
    }
  }
}

__device__ __forceinline__ void compute_h(
    int e0, int lane, const float* __restrict__ e_feat,
    const int* __restrict__ src, const int* __restrict__ dst,
    const unsigned* __restrict__ P1p, const unsigned* __restrict__ P2p,
    const float* __restrict__ bn_, const bf16x8* Bf,
    float h[8][4], int dIdx[4]) {
  const int c = lane & 15, q = lane >> 4;
  const float* er = e_feat + (size_t)(e0 + c) * 64 + q * 8;
  f32x4 a0 = __builtin_nontemporal_load((const f32x4*)er);
  f32x4 a1 = __builtin_nontemporal_load((const f32x4*)(er + 4));
  f32x4 a2 = __builtin_nontemporal_load((const f32x4*)(er + 32));
  f32x4 a3 = __builtin_nontemporal_load((const f32x4*)(er + 36));
  int sIdx[4];
#pragma unroll
  for (int r = 0; r < 4; ++r) {
    dIdx[r] = dst[e0 + q * 4 + r];
    sIdx[r] = src[e0 + q * 4 + r];
  }
  bf16x8 A0, A1;
#pragma unroll
  for (int j = 0; j < 4; ++j) {
    A0[j] = (__bf16)a0[j]; A0[4 + j] = (__bf16)a1[j];
    A1[j] = (__bf16)a2[j]; A1[4 + j] = (__bf16)a3[j];
  }
  f32x4 acc[8];
#pragma unroll
  for (int nt = 0; nt < 8; ++nt) {
    acc[nt] = (f32x4){0.f, 0.f, 0.f, 0.f};
    acc[nt] = __builtin_amdgcn_mfma_f32_16x16x32_bf16(A0, Bf[nt * 2 + 0], acc[nt], 0, 0, 0);
    acc[nt] = __builtin_amdgcn_mfma_f32_16x16x32_bf16(A1, Bf[nt * 2 + 1], acc[nt], 0, 0, 0);
  }
  // P1/P2 packed-bf16 gathers: one dword gives chans {n, n+64}
#pragma unroll
  for (int r = 0; r < 4; ++r) {
    const unsigned* p1r = P1p + (size_t)dIdx[r] * 64 + c;
    const unsigned* p2r = P2p + (size_t)sIdx[r] * 64 + c;
#pragma unroll
    for (int ntp = 0; ntp < 4; ++ntp) {
      unsigned u1 = p1r[ntp * 16];
      unsigned u2 = p2r[ntp * 16];
      float lo = __uint_as_float(u1 << 16) + __uint_as_float(u2 << 16);
      float hi = __uint_as_float(u1 & 0xffff0000u) + __uint_as_float(u2 & 0xffff0000u);
      h[ntp][r]     = acc[ntp][r]     + lo + bn_[ntp];
      h[ntp + 4][r] = acc[ntp + 4][r] + hi + bn_[ntp + 4];
    }
  }
}

// ---------------------------------------------------------------------------
// Kernel 2: compute h, accumulate BN1 stats; if hbuf != null, also materialize
// h as packed bf16x2 {filt(chan n), core(chan n+64)} at hbuf[e*64 + n].
__global__ __launch_bounds__(256, 3) void k_edge_h(
    const float* __restrict__ e_feat, const int* __restrict__ src,
    const int* __restrict__ dst, const float* __restrict__ W,
    const float* __restrict__ b, const unsigned* __restrict__ P1p,
    const unsigned* __restrict__ P2p, float* __restrict__ stats1,
    unsigned int* __restrict__ hbuf) {
  const int tid = threadIdx.x, lane = tid & 63, w = tid >> 6;
  const int c = lane & 15, q = lane >> 4;
  bf16x8 Bf[16];
  load_W3_frags(W, lane, Bf);
  float bn_[8];
#pragma unroll
  for (int nt = 0; nt < 8; ++nt) bn_[nt] = b[nt * 16 + c];
  float sums[8] = {0, 0, 0, 0, 0, 0, 0, 0};
  float sqs[8]  = {0, 0, 0, 0, 0, 0, 0, 0};
  for (int g0 = blockIdx.x * 64; g0 < N_EDGES; g0 += gridDim.x * 64) {
    const int e0 = g0 + w * 16;
    float h[8][4]; int dIdx[4];
    compute_h(e0, lane, e_feat, src, dst, P1p, P2p, bn_, Bf, h, dIdx);
#pragma unroll
    for (int nt = 0; nt < 8; ++nt)
#pragma unroll
      for (int r = 0; r < 4; ++r) {
        sums[nt] += h[nt][r];
        sqs[nt]  += h[nt][r] * h[nt][r];
      }
    if (hbuf) {
#pragma unroll
      for (int r = 0; r < 4; ++r) {
        unsigned int* hb = hbuf + (size_t)(e0 + q * 4 + r) * 64 + c;
#pragma unroll
        for (int nt = 0; nt < 4; ++nt)
          __builtin_nontemporal_store(pack_bf16x2(h[nt][r], h[nt + 4][r]), hb + nt * 16);
      }
    }
  }
  __shared__ float red[4][256];
#pragma unroll
  for (int nt = 0; nt < 8; ++nt) {
    float s = sums[nt]; s += __shfl_xor(s, 16, 64); s += __shfl_xor(s, 32, 64);
    float qv = sqs[nt]; qv += __shfl_xor(qv, 16, 64); qv += __shfl_xor(qv, 32, 64);
    if (lane < 16) { red[w][nt * 16 + lane] = s; red[w][128 + nt * 16 + lane] = qv; }
  }
  __syncthreads();
  float v = red[0][tid] + red[1][tid] + red[2][tid] + red[3][tid];
  unsafeAtomicAdd(&stats1[tid], v);
}

// Kernel 3: fold BN1 into per-channel affine.
__global__ void k_finalize1(const float* __restrict__ stats1,
                            const float* __restrict__ g1,
                            const float* __restrict__ beta1,
                            float* __restrict__ ss1) {
  int t = threadIdx.x;
  if (t < 128) {
    float inv_n = 1.f / (float)N_EDGES;
    float mu  = stats1[t] * inv_n;
    float var = stats1[128 + t] * inv_n - mu * mu;
    float sc  = g1[t] * rsqrtf(var + BN_EPS);
    ss1[t] = sc;
    ss1[128 + t] = beta1[t] - mu * sc;
  }
}

// ---------------------------------------------------------------------------
// Counting sort of edge ids by dst.
__global__ __launch_bounds__(256) void k_hist(const int* __restrict__ dst,
                                              unsigned* __restrict__ deg) {
  int e = blockIdx.x * 256 + threadIdx.x;
  if (e < N_EDGES) atomicAdd(&deg[dst[e]], 1u);
}

#define SCAN_THREADS 1024
__global__ __launch_bounds__(SCAN_THREADS) void k_scan(
    const unsigned* __restrict__ deg, unsigned* __restrict__ offs,
    unsigned* __restrict__ cursor) {
  const int t = threadIdx.x;
  const int CH = (N_NODES + SCAN_THREADS - 1) / SCAN_THREADS;   // 49
  const int base = t * CH;
  unsigned s = 0;
  for (int i = 0; i < CH; ++i) {
    int idx = base + i;
    if (idx < N_NODES) s += deg[idx];
  }
  __shared__ unsigned ps[SCAN_THREADS];
  ps[t] = s; __syncthreads();
  for (int off = 1; off < SCAN_THREADS; off <<= 1) {
    unsigned mine = ps[t];
    unsigned other = (t >= off) ? ps[t - off] : 0u;
    __syncthreads();
    ps[t] = mine + other;
    __syncthreads();
  }
  unsigned run = ps[t] - s;                 // exclusive prefix of this chunk
  for (int i = 0; i < CH; ++i) {
    int idx = base + i;
    if (idx < N_NODES) {
      offs[idx] = run; cursor[idx] = run;
      run += deg[idx];
    }
  }
  if (t == SCAN_THREADS - 1) offs[N_NODES] = run;
}

__global__ __launch_bounds__(256) void k_scatter_ids(
    const int* __restrict__ dst, unsigned* __restrict__ cursor,
    unsigned* __restrict__ perm) {
  int e = blockIdx.x * 256 + threadIdx.x;
  if (e < N_EDGES) {
    unsigned pos = atomicAdd(&cursor[dst[e]], 1u);
    perm[pos] = e;
  }
}

// ---------------------------------------------------------------------------
// Kernel 4 (sorted): gather per-node edges, BN1 affine, msg=sigmoid*softplus,
// register-accumulate, write agg row once. Fuses BN2 stats (no k_agg_stats,
// no agg memset, zero atomics on agg).
__global__ __launch_bounds__(256) void k_gather_msg(
    const unsigned int* __restrict__ hbuf, const unsigned* __restrict__ perm,
    const unsigned* __restrict__ offs, const float* __restrict__ ss1,
    float* __restrict__ agg, float* __restrict__ stats2) {
  const int tid = threadIdx.x, lane = tid & 63, w = tid >> 6;
  const float sc_f = ss1[lane], sc_g = ss1[64 + lane];
  const float sh_f = ss1[128 + lane], sh_g = ss1[192 + lane];
  const int wave_id = blockIdx.x * 4 + w;
  const int n_waves = gridDim.x * 4;
  float ssum = 0.f, ssq = 0.f;
  for (int node = wave_id; node < N_NODES; node += n_waves) {
    const int start = (int)offs[node], end = (int)offs[node + 1];
    float acc = 0.f;
    int j = start;
    const int e4 = start + ((end - start) & ~3);
    for (; j < e4; j += 4) {
      unsigned e0 = perm[j], e1 = perm[j + 1], e2 = perm[j + 2], e3 = perm[j + 3];
      unsigned p0 = __builtin_nontemporal_load(hbuf + (size_t)e0 * 64 + lane);
      unsigned p1 = __builtin_nontemporal_load(hbuf + (size_t)e1 * 64 + lane);
      unsigned p2 = __builtin_nontemporal_load(hbuf + (size_t)e2 * 64 + lane);
      unsigned p3 = __builtin_nontemporal_load(hbuf + (size_t)e3 * 64 + lane);
      float f0 = __uint_as_float(p0 << 16) * sc_f + sh_f;
      float g0 = __uint_as_float(p0 & 0xffff0000u) * sc_g + sh_g;
      float f1 = __uint_as_float(p1 << 16) * sc_f + sh_f;
      float g1 = __uint_as_float(p1 & 0xffff0000u) * sc_g + sh_g;
      float f2 = __uint_as_float(p2 << 16) * sc_f + sh_f;
      float g2 = __uint_as_float(p2 & 0xffff0000u) * sc_g + sh_g;
      float f3 = __uint_as_float(p3 << 16) * sc_f + sh_f;
      float g3 = __uint_as_float(p3 & 0xffff0000u) * sc_g + sh_g;
      acc += fast_sigmoid(f0) * fast_softplus(g0);
      acc += fast_sigmoid(f1) * fast_softplus(g1);
      acc += fast_sigmoid(f2) * fast_softplus(g2);
      acc += fast_sigmoid(f3) * fast_softplus(g3);
    }
    for (; j < end; ++j) {
      unsigned e = perm[j];
      unsigned p = __builtin_nontemporal_load(hbuf + (size_t)e * 64 + lane);
      float f = __uint_as_float(p << 16) * sc_f + sh_f;
      float g = __uint_as_float(p & 0xffff0000u) * sc_g + sh_g;
      acc += fast_sigmoid(f) * fast_softplus(g);
    }
    agg[(size_t)node * 64 + lane] = acc;
    ssum += acc; ssq += acc * acc;
  }
  __shared__ float red[4][64], redq[4][64];
  red[w][lane] = ssum; redq[w][lane] = ssq;
  __syncthreads();
  if (tid < 64) {
    unsafeAtomicAdd(&stats2[tid], red[0][tid] + red[1][tid] + red[2][tid] + red[3][tid]);
  } else if (tid < 128) {
    int t = tid - 64;
    unsafeAtomicAdd(&stats2[64 + t], redq[0][t] + redq[1][t] + redq[2][t] + redq[3][t]);
  }
}

// ---------------------------------------------------------------------------
// Kernel 4 (fallback, atomic): read packed h, BN1 affine, msg, scatter.
__global__ __launch_bounds__(256) void k_msg_scatter(
    const unsigned int* __restrict__ hbuf, const int* __restrict__ dst,
    const float* __restrict__ ss1, float* __restrict__ agg) {
  const int tid = threadIdx.x, lane = tid & 63, w = tid >> 6;
  const float sc_f = ss1[lane], sc_g = ss1[64 + lane];
  const float sh_f = ss1[128 + lane], sh_g = ss1[192 + lane];
  const int wave_id = blockIdx.x * 4 + w;
  const int n_waves = gridDim.x * 4;
  for (int e0 = wave_id * 8; e0 < N_EDGES; e0 += n_waves * 8) {
    unsigned int p[8];
    int d[8];
#pragma unroll
    for (int j = 0; j < 8; ++j) {
      p[j] = __builtin_nontemporal_load(hbuf + (size_t)(e0 + j) * 64 + lane);
      d[j] = __builtin_amdgcn_readfirstlane(dst[e0 + j]);
    }
#pragma unroll
    for (int j = 0; j < 8; ++j) {
      float f = __uint_as_float(p[j] << 16)          * sc_f + sh_f;
      float g = __uint_as_float(p[j] & 0xffff0000u)  * sc_g + sh_g;
      unsafeAtomicAdd(&agg[(size_t)d[j] * 64 + lane], fast_sigmoid(f) * fast_softplus(g));
    }
  }
}

// Fallback pass 2 (recompute h) if ws_size is too small for hbuf.
__global__ __launch_bounds__(256, 3) void k_edge_msg(
    const float* __restrict__ e_feat, const int* __restrict__ src,
    const int* __restrict__ dst, const float* __restrict__ W,
    const float* __restrict__ b, const unsigned* __restrict__ P1p,
    const unsigned* __restrict__ P2p, const float* __restrict__ ss1,
    float* __restrict__ agg) {
  const int tid = threadIdx.x, lane = tid & 63, w = tid >> 6;
  const int c = lane & 15;
  bf16x8 Bf[16];
  load_W3_frags(W, lane, Bf);
  float bn_[8], sc[8], sh[8];
#pragma unroll
  for (int nt = 0; nt < 8; ++nt) {
    bn_[nt] = b[nt * 16 + c];
    sc[nt]  = ss1[nt * 16 + c];
    sh[nt]  = ss1[128 + nt * 16 + c];
  }
  for (int g0 = blockIdx.x * 64; g0 < N_EDGES; g0 += gridDim.x * 64) {
    const int e0 = g0 + w * 16;
    float h[8][4]; int dIdx[4];
    compute_h(e0, lane, e_feat, src, dst, P1p, P2p, bn_, Bf, h, dIdx);
#pragma unroll
    for (int nt = 0; nt < 4; ++nt) {
#pragma unroll
      for (int r = 0; r < 4; ++r) {
        float f = h[nt][r] * sc[nt] + sh[nt];
        float g = h[nt + 4][r] * sc[nt + 4] + sh[nt + 4];
        unsafeAtomicAdd(&agg[(size_t)dIdx[r] * 64 + nt * 16 + c],
                        fast_sigmoid(f) * fast_softplus(g));
      }
    }
  }
}

// Kernel 5: BN2 stats over agg rows (fallback paths only).
__global__ __launch_bounds__(256) void k_agg_stats(const float* __restrict__ agg,
                                                   float* __restrict__ stats2) {
  const int tid = threadIdx.x;
  const int c = tid & 63, w = tid >> 6;
  float s = 0.f, sq = 0.f;
  for (int r = blockIdx.x * 4 + w; r < N_NODES; r += gridDim.x * 4) {
    float v = agg[(size_t)r * 64 + c];
    s += v; sq += v * v;
  }
  __shared__ float ws_[4][64], wq_[4][64];
  ws_[w][c] = s; wq_[w][c] = sq;
  __syncthreads();
  if (tid < 64) {
    unsafeAtomicAdd(&stats2[tid], ws_[0][tid] + ws_[1][tid] + ws_[2][tid] + ws_[3][tid]);
  } else if (tid < 128) {
    int t = tid - 64;
    unsafeAtomicAdd(&stats2[64 + t], wq_[0][t] + wq_[1][t] + wq_[2][t] + wq_[3][t]);
  }
}

__global__ void k_finalize2(const float* __restrict__ stats2,
                            const float* __restrict__ g2,
                            const float* __restrict__ beta2,
                            float* __restrict__ ss2) {
  int t = threadIdx.x;
  if (t < 64) {
    float inv_n = 1.f / (float)N_NODES;
    float mu  = stats2[t] * inv_n;
    float var = stats2[64 + t] * inv_n - mu * mu;
    float sc  = g2[t] * rsqrtf(var + BN_EPS);
    ss2[t] = sc;
    ss2[64 + t] = beta2[t] - mu * sc;
  }
}

// Kernel 7: out = softplus(BN2(agg) + n_feat), float4-vectorized.
__global__ __launch_bounds__(256) void k_output(const float* __restrict__ agg,
                                                const float* __restrict__ n_feat,
                                                const float* __restrict__ ss2,
                                                float* __restrict__ out) {
  int i = blockIdx.x * 256 + threadIdx.x;
  if (i >= N_NODES * 16) return;
  int cb = (i & 15) * 4;
  float4 a = ((const float4*)agg)[i];
  float4 x = ((const float4*)n_feat)[i];
  float4 r;
  r.x = fast_softplus(a.x * ss2[cb + 0] + ss2[64 + cb + 0] + x.x);
  r.y = fast_softplus(a.y * ss2[cb + 1] + ss2[64 + cb + 1] + x.y);
  r.z = fast_softplus(a.z * ss2[cb + 2] + ss2[64 + cb + 2] + x.z);
  r.w = fast_softplus(a.w * ss2[cb + 3] + ss2[64 + cb + 3] + x.w);
  ((float4*)out)[i] = r;
}

extern "C" void kernel_launch(void* const* d_in, const int* in_sizes, int n_in,
                              void* d_out, int out_size, void* d_ws, size_t ws_size,
                              hipStream_t stream) {
  const float* n_feat = (const float*)d_in[0];
  const float* e_feat = (const float*)d_in[1];
  const int*   src    = (const int*)d_in[2];
  const int*   dst    = (const int*)d_in[3];
  const float* W      = (const float*)d_in[4];
  const float* b      = (const float*)d_in[5];
  const float* g1     = (const float*)d_in[6];
  const float* beta1  = (const float*)d_in[7];
  const float* g2     = (const float*)d_in[8];
  const float* beta2  = (const float*)d_in[9];

  unsigned* ws  = (unsigned*)d_ws;
  unsigned* P1p = ws;
  unsigned* P2p = ws + OFF_P2P;
  float* agg    = (float*)(ws + OFF_AGG);
  float* stats1 = (float*)(ws + OFF_STATS1);
  float* ss1    = stats1 + 256;
  float* stats2 = ss1 + 256;
  float* ss2    = stats2 + 128;
  unsigned int* hbuf = ws + OFF_HBUF;
  unsigned* perm   = ws + OFF_PERM;
  unsigned* offs   = ws + OFF_OFFS;
  unsigned* deg    = ws + OFF_DEG;
  unsigned* cursor = ws + OFF_CURS;
  float* out    = (float*)d_out;

  const bool have_hbuf = ws_size >= WS_WORDS_NEEDED * 4;
  const bool have_sort = ws_size >= WS_WORDS_SORTED * 4;

  hipMemsetAsync(stats1, 0, (256 + 256 + 128 + 128) * sizeof(float), stream);

  if (have_sort) {
    // counting sort of edges by dst (only needs dst; runs before edge pass)
    hipMemsetAsync(deg, 0, N_NODES * sizeof(unsigned), stream);
    k_hist<<<(N_EDGES + 255) / 256, 256, 0, stream>>>(dst, deg);
    k_scan<<<1, SCAN_THREADS, 0, stream>>>(deg, offs, cursor);
    k_scatter_ids<<<(N_EDGES + 255) / 256, 256, 0, stream>>>(dst, cursor, perm);

    k_precompute<<<1024, 256, 0, stream>>>(n_feat, W, P1p, P2p);
    k_edge_h<<<2048, 256, 0, stream>>>(e_feat, src, dst, W, b, P1p, P2p, stats1, hbuf);
    k_finalize1<<<1, 128, 0, stream>>>(stats1, g1, beta1, ss1);
    // gather per node: no atomics, writes agg exactly once, fuses BN2 stats
    k_gather_msg<<<2048, 256, 0, stream>>>(hbuf, perm, offs, ss1, agg, stats2);
  } else {
    hipMemsetAsync(agg, 0, (size_t)N_NODES * 64 * sizeof(float), stream);
    k_precompute<<<1024, 256, 0, stream>>>(n_feat, W, P1p, P2p);
    if (have_hbuf) {
      k_edge_h<<<2048, 256, 0, stream>>>(e_feat, src, dst, W, b, P1p, P2p, stats1, hbuf);
      k_finalize1<<<1, 128, 0, stream>>>(stats1, g1, beta1, ss1);
      k_msg_scatter<<<2048, 256, 0, stream>>>(hbuf, dst, ss1, agg);
    } else {
      k_edge_h<<<2048, 256, 0, stream>>>(e_feat, src, dst, W, b, P1p, P2p, stats1, nullptr);
      k_finalize1<<<1, 128, 0, stream>>>(stats1, g1, beta1, ss1);
      k_edge_msg<<<2048, 256, 0, stream>>>(e_feat, src, dst, W, b, P1p, P2p, ss1, agg);
    }
    k_agg_stats<<<512, 256, 0, stream>>>(agg, stats2);
  }
  k_finalize2<<<1, 64, 0, stream>>>(stats2, g2, beta2, ss2);
  k_output<<<3125, 256, 0, stream>>>(agg, n_feat, ss2, out);
}

// Round 2
// 662.248 us; speedup vs baseline: 1.1718x; 1.1718x over previous
//
#include <hip/hip_runtime.h>
#include <math.h>

// Problem constants (from reference)
#define N_NODES 50000
#define N_EDGES 800000
#define IN_DIM  192      // 2*O + ED
#define BN_EPS  1e-5f

// Workspace layout (4-byte word offsets):
//   P1p    [N,64]  uint @ 0          packed bf16x2 {chan n, chan n+64} of n_feat@W1^T
//   P2p    [N,64]  uint @ 3,200,000  same for W2^T
//   agg    [N,64]  f32  @ 6,400,000
//   stats1 [256]   f32  @ 9,600,000  (sum[128], sumsq[128])
//   ss1    [256]   f32  @ +256       (scale[128], shift[128])
//   stats2 [128]   f32  @ +512
//   ss2    [128]   f32  @ +640
//   hbuf   [E,64]  uint @ 9,601,024  packed bf16x2 {filt,core} per SORTED slot
//   perm   [E]     uint @ OFF_PERM   edge ids sorted by dst (counting sort)
//   offs   [N+1]   uint @ OFF_OFFS   CSR row offsets per dst node
//   deg    [N]     uint @ OFF_DEG    histogram scratch
//   cursor [N]     uint @ OFF_CURS   scatter cursors (copy of offs)
//   bsum   [256]   uint @ OFF_BSUM   per-block sums for hierarchical scan
#define OFF_P2P    3200000
#define OFF_AGG    6400000
#define OFF_STATS1 9600000
#define OFF_HBUF   9601024
#define WS_WORDS_NEEDED (OFF_HBUF + (size_t)N_EDGES * 64)
#define OFF_PERM   (OFF_HBUF + (size_t)N_EDGES * 64)
#define OFF_OFFS   (OFF_PERM + N_EDGES)
#define OFF_DEG    (OFF_OFFS + N_NODES + 1)
#define OFF_CURS   (OFF_DEG + N_NODES)
#define OFF_BSUM   (OFF_CURS + N_NODES)
#define WS_WORDS_SORTED (OFF_BSUM + 256)

#define NSCAN_BLOCKS 196   // ceil(50000/256)

typedef __bf16 bf16x8 __attribute__((ext_vector_type(8)));
typedef __bf16 bf16x2 __attribute__((ext_vector_type(2)));
typedef float  f32x4  __attribute__((ext_vector_type(4)));

__device__ __forceinline__ unsigned pack_bf16x2(float lo, float hi) {
  union { bf16x2 v; unsigned u; } pk;
  pk.v[0] = (__bf16)lo; pk.v[1] = (__bf16)hi;
  return pk.u;
}
// fast transcendentals (native v_exp/v_log/v_rcp)
__device__ __forceinline__ float fast_sigmoid(float f) {
  return __builtin_amdgcn_rcpf(1.f + __expf(-f));
}
__device__ __forceinline__ float fast_softplus(float g) {
  return fmaxf(g, 0.f) + __logf(1.f + __expf(-fabsf(g)));
}

// ---------------------------------------------------------------------------
// Kernel 1: P1p[n][o] = pack(bf16(n_feat[n]·W[o][0:64]), bf16(n_feat[n]·W[o+64][0:64]))
//           P2p same with k-range 64:128.
// Also (if deg != null) fused histogram of dst for the counting sort.
__global__ __launch_bounds__(256) void k_precompute(
    const float* __restrict__ n_feat, const float* __restrict__ W,
    unsigned* __restrict__ P1p, unsigned* __restrict__ P2p,
    const int* __restrict__ dst, unsigned* __restrict__ deg) {
  const int tid = threadIdx.x;
  if (deg) {
    for (int e = blockIdx.x * 256 + tid; e < N_EDGES; e += gridDim.x * 256)
      atomicAdd(&deg[dst[e]], 1u);
  }
  const int o   = tid & 63;
  const int sel = tid >> 6;                 // 0..3
  const int ch  = o + (sel & 1) * 64;
  const int kb  = (sel & 2) ? 64 : 0;
  float4 wreg[16];
  const float* wrow = W + (size_t)ch * IN_DIM + kb;
#pragma unroll
  for (int i = 0; i < 16; ++i) wreg[i] = *(const float4*)(wrow + i * 4);
  __shared__ float xrow[4][64];
  __shared__ float accbuf[4][4][64];        // [sel][r][o]
  for (int r0 = blockIdx.x * 4; r0 < N_NODES; r0 += gridDim.x * 4) {
    __syncthreads();
    xrow[tid >> 6][tid & 63] = n_feat[(size_t)(r0 + (tid >> 6)) * 64 + (tid & 63)];
    __syncthreads();
    float acc[4] = {0.f, 0.f, 0.f, 0.f};
#pragma unroll
    for (int kk = 0; kk < 16; ++kk) {
      float4 wv = wreg[kk];
#pragma unroll
      for (int r = 0; r < 4; ++r) {
        float4 xv = *(const float4*)&xrow[r][kk * 4];
        acc[r] += wv.x * xv.x + wv.y * xv.y + wv.z * xv.z + wv.w * xv.w;
      }
    }
#pragma unroll
    for (int r = 0; r < 4; ++r) accbuf[sel][r][o] = acc[r];
    __syncthreads();
    // thread (o, sel) packs+writes node row r0+sel
    const size_t rr = (size_t)(r0 + sel) * 64 + o;
    P1p[rr] = pack_bf16x2(accbuf[0][sel][o], accbuf[1][sel][o]);
    P2p[rr] = pack_bf16x2(accbuf[2][sel][o], accbuf[3][sel][o]);
  }
}

// ---------------------------------------------------------------------------
// Hierarchical exclusive scan of deg[N_NODES] -> offs/cursor.
// scan1: per-block (256 elems) sums.
__global__ __launch_bounds__(256) void k_scan1(const unsigned* __restrict__ deg,
                                               unsigned* __restrict__ bsum) {
  const int t = threadIdx.x;
  const int i = blockIdx.x * 256 + t;
  __shared__ unsigned r[256];
  r[t] = (i < N_NODES) ? deg[i] : 0u;
  __syncthreads();
  for (int off = 128; off > 0; off >>= 1) {
    if (t < off) r[t] += r[t + off];
    __syncthreads();
  }
  if (t == 0) bsum[blockIdx.x] = r[0];
}

// scan2: each block redundantly scans bsum[196] (cheap), then local scan.
__global__ __launch_bounds__(256) void k_scan2(const unsigned* __restrict__ deg,
                                               const unsigned* __restrict__ bsum,
                                               unsigned* __restrict__ offs,
                                               unsigned* __restrict__ cursor) {
  const int t = threadIdx.x;
  __shared__ unsigned sb[256];
  sb[t] = (t < NSCAN_BLOCKS) ? bsum[t] : 0u;
  __syncthreads();
  for (int off = 1; off < 256; off <<= 1) {
    unsigned add = (t >= off) ? sb[t - off] : 0u;
    __syncthreads();
    sb[t] += add;
    __syncthreads();
  }
  const unsigned base = (blockIdx.x == 0) ? 0u : sb[blockIdx.x - 1];
  const int i = blockIdx.x * 256 + t;
  const unsigned v = (i < N_NODES) ? deg[i] : 0u;
  __shared__ unsigned sd[256];
  sd[t] = v;
  __syncthreads();
  for (int off = 1; off < 256; off <<= 1) {
    unsigned add = (t >= off) ? sd[t - off] : 0u;
    __syncthreads();
    sd[t] += add;
    __syncthreads();
  }
  const unsigned excl = base + sd[t] - v;
  if (i < N_NODES) { offs[i] = excl; cursor[i] = excl; }
  if (blockIdx.x == 0 && t == 0) offs[N_NODES] = N_EDGES;
}

__global__ __launch_bounds__(256) void k_scatter_ids(
    const int* __restrict__ dst, unsigned* __restrict__ cursor,
    unsigned* __restrict__ perm) {
  int e = blockIdx.x * 256 + threadIdx.x;
  if (e < N_EDGES) {
    unsigned pos = atomicAdd(&cursor[dst[e]], 1u);
    perm[pos] = e;
  }
}

// ---------------------------------------------------------------------------
// MFMA edge-pass core.  Wave computes h[16 slots][128 ch] for slot base e0.
// If perm != null, slot j holds edge perm[j] (dst-sorted order); else edge j.
//   Q = e_feat_tile(bf16) @ W3^T(bf16) via 16x16x32 MFMA, f32 accumulate.
//   D-frag: lane holds D[m=(lane>>4)*4+r][n=nt*16+(lane&15)]
__device__ __forceinline__ void load_W3_frags(const float* __restrict__ W,
                                              int lane, bf16x8* Bf) {
  const int c = lane & 15, q = lane >> 4;
#pragma unroll
  for (int nt = 0; nt < 8; ++nt) {
#pragma unroll
    for (int ks = 0; ks < 2; ++ks) {
      const float* wr = W + (size_t)(nt * 16 + c) * IN_DIM + 128 + ks * 32 + q * 8;
      f32x4 w0 = *(const f32x4*)wr;
      f32x4 w1 = *(const f32x4*)(wr + 4);
      bf16x8 f;
#pragma unroll
      for (int j = 0; j < 4; ++j) { f[j] = (__bf16)w0[j]; f[4 + j] = (__bf16)w1[j]; }
      Bf[nt * 2 + ks] = f;
    }
  }
}

__device__ __forceinline__ void compute_h(
    int e0, int lane, const unsigned* __restrict__ perm,
    const float* __restrict__ e_feat,
    const int* __restrict__ src, const int* __restrict__ dst,
    const unsigned* __restrict__ P1p, const unsigned* __restrict__ P2p,
    const float* __restrict__ bn_, const bf16x8* Bf,
    float h[8][4], int dIdx[4]) {
  const int c = lane & 15, q = lane >> 4;
  const int eA = perm ? (int)perm[e0 + c] : (e0 + c);
  const float* er = e_feat + (size_t)eA * 64 + q * 8;
  f32x4 a0 = __builtin_nontemporal_load((const f32x4*)er);
  f32x4 a1 = __builtin_nontemporal_load((const f32x4*)(er + 4));
  f32x4 a2 = __builtin_nontemporal_load((const f32x4*)(er + 32));
  f32x4 a3 = __builtin_nontemporal_load((const f32x4*)(er + 36));
  int sIdx[4];
#pragma unroll
  for (int r = 0; r < 4; ++r) {
    const int sl = e0 + q * 4 + r;
    const int ee = perm ? (int)perm[sl] : sl;
    dIdx[r] = dst[ee];
    sIdx[r] = src[ee];
  }
  bf16x8 A0, A1;
#pragma unroll
  for (int j = 0; j < 4; ++j) {
    A0[j] = (__bf16)a0[j]; A0[4 + j] = (__bf16)a1[j];
    A1[j] = (__bf16)a2[j]; A1[4 + j] = (__bf16)a3[j];
  }
  f32x4 acc[8];
#pragma unroll
  for (int nt = 0; nt < 8; ++nt) {
    acc[nt] = (f32x4){0.f, 0.f, 0.f, 0.f};
    acc[nt] = __builtin_amdgcn_mfma_f32_16x16x32_bf16(A0, Bf[nt * 2 + 0], acc[nt], 0, 0, 0);
    acc[nt] = __builtin_amdgcn_mfma_f32_16x16x32_bf16(A1, Bf[nt * 2 + 1], acc[nt], 0, 0, 0);
  }
  // P1/P2 packed-bf16 gathers: one dword gives chans {n, n+64}
#pragma unroll
  for (int r = 0; r < 4; ++r) {
    const unsigned* p1r = P1p + (size_t)dIdx[r] * 64 + c;
    const unsigned* p2r = P2p + (size_t)sIdx[r] * 64 + c;
#pragma unroll
    for (int ntp = 0; ntp < 4; ++ntp) {
      unsigned u1 = p1r[ntp * 16];
      unsigned u2 = p2r[ntp * 16];
      float lo = __uint_as_float(u1 << 16) + __uint_as_float(u2 << 16);
      float hi = __uint_as_float(u1 & 0xffff0000u) + __uint_as_float(u2 & 0xffff0000u);
      h[ntp][r]     = acc[ntp][r]     + lo + bn_[ntp];
      h[ntp + 4][r] = acc[ntp + 4][r] + hi + bn_[ntp + 4];
    }
  }
}

// ---------------------------------------------------------------------------
// Kernel 2: compute h (slot order), accumulate BN1 stats; if hbuf != null,
// materialize h as packed bf16x2 {filt,core} at hbuf[slot*64 + n].
__global__ __launch_bounds__(256, 3) void k_edge_h(
    const float* __restrict__ e_feat, const int* __restrict__ src,
    const int* __restrict__ dst, const float* __restrict__ W,
    const float* __restrict__ b, const unsigned* __restrict__ P1p,
    const unsigned* __restrict__ P2p, const unsigned* __restrict__ perm,
    float* __restrict__ stats1, unsigned int* __restrict__ hbuf) {
  const int tid = threadIdx.x, lane = tid & 63, w = tid >> 6;
  const int c = lane & 15, q = lane >> 4;
  bf16x8 Bf[16];
  load_W3_frags(W, lane, Bf);
  float bn_[8];
#pragma unroll
  for (int nt = 0; nt < 8; ++nt) bn_[nt] = b[nt * 16 + c];
  float sums[8] = {0, 0, 0, 0, 0, 0, 0, 0};
  float sqs[8]  = {0, 0, 0, 0, 0, 0, 0, 0};
  for (int g0 = blockIdx.x * 64; g0 < N_EDGES; g0 += gridDim.x * 64) {
    const int e0 = g0 + w * 16;
    float h[8][4]; int dIdx[4];
    compute_h(e0, lane, perm, e_feat, src, dst, P1p, P2p, bn_, Bf, h, dIdx);
#pragma unroll
    for (int nt = 0; nt < 8; ++nt)
#pragma unroll
      for (int r = 0; r < 4; ++r) {
        sums[nt] += h[nt][r];
        sqs[nt]  += h[nt][r] * h[nt][r];
      }
    if (hbuf) {
#pragma unroll
      for (int r = 0; r < 4; ++r) {
        unsigned int* hb = hbuf + (size_t)(e0 + q * 4 + r) * 64 + c;
#pragma unroll
        for (int nt = 0; nt < 4; ++nt)
          __builtin_nontemporal_store(pack_bf16x2(h[nt][r], h[nt + 4][r]), hb + nt * 16);
      }
    }
  }
  __shared__ float red[4][256];
#pragma unroll
  for (int nt = 0; nt < 8; ++nt) {
    float s = sums[nt]; s += __shfl_xor(s, 16, 64); s += __shfl_xor(s, 32, 64);
    float qv = sqs[nt]; qv += __shfl_xor(qv, 16, 64); qv += __shfl_xor(qv, 32, 64);
    if (lane < 16) { red[w][nt * 16 + lane] = s; red[w][128 + nt * 16 + lane] = qv; }
  }
  __syncthreads();
  float v = red[0][tid] + red[1][tid] + red[2][tid] + red[3][tid];
  unsafeAtomicAdd(&stats1[tid], v);
}

// Kernel 3: fold BN1 into per-channel affine.
__global__ void k_finalize1(const float* __restrict__ stats1,
                            const float* __restrict__ g1,
                            const float* __restrict__ beta1,
                            float* __restrict__ ss1) {
  int t = threadIdx.x;
  if (t < 128) {
    float inv_n = 1.f / (float)N_EDGES;
    float mu  = stats1[t] * inv_n;
    float var = stats1[128 + t] * inv_n - mu * mu;
    float sc  = g1[t] * rsqrtf(var + BN_EPS);
    ss1[t] = sc;
    ss1[128 + t] = beta1[t] - mu * sc;
  }
}

// ---------------------------------------------------------------------------
// Kernel 4 (sorted): hbuf is in dst-sorted slot order, so node n owns the
// contiguous slot range [offs[n], offs[n+1]).  Pure streaming read, BN1
// affine, msg=sigmoid*softplus, register-accumulate, single agg write.
// Fuses BN2 stats (no k_agg_stats, no agg memset, zero atomics on agg).
__global__ __launch_bounds__(256) void k_gather_msg(
    const unsigned int* __restrict__ hbuf, const unsigned* __restrict__ offs,
    const float* __restrict__ ss1, float* __restrict__ agg,
    float* __restrict__ stats2) {
  const int tid = threadIdx.x, lane = tid & 63, w = tid >> 6;
  const float sc_f = ss1[lane], sc_g = ss1[64 + lane];
  const float sh_f = ss1[128 + lane], sh_g = ss1[192 + lane];
  const int wave_id = blockIdx.x * 4 + w;
  const int n_waves = gridDim.x * 4;
  float ssum = 0.f, ssq = 0.f;
  for (int node = wave_id; node < N_NODES; node += n_waves) {
    const int start = (int)offs[node], end = (int)offs[node + 1];
    float acc = 0.f;
    int j = start;
    const int e4 = start + ((end - start) & ~3);
    for (; j < e4; j += 4) {
      unsigned p0 = __builtin_nontemporal_load(hbuf + (size_t)j * 64 + lane);
      unsigned p1 = __builtin_nontemporal_load(hbuf + (size_t)(j + 1) * 64 + lane);
      unsigned p2 = __builtin_nontemporal_load(hbuf + (size_t)(j + 2) * 64 + lane);
      unsigned p3 = __builtin_nontemporal_load(hbuf + (size_t)(j + 3) * 64 + lane);
      float f0 = __uint_as_float(p0 << 16) * sc_f + sh_f;
      float g0 = __uint_as_float(p0 & 0xffff0000u) * sc_g + sh_g;
      float f1 = __uint_as_float(p1 << 16) * sc_f + sh_f;
      float g1 = __uint_as_float(p1 & 0xffff0000u) * sc_g + sh_g;
      float f2 = __uint_as_float(p2 << 16) * sc_f + sh_f;
      float g2 = __uint_as_float(p2 & 0xffff0000u) * sc_g + sh_g;
      float f3 = __uint_as_float(p3 << 16) * sc_f + sh_f;
      float g3 = __uint_as_float(p3 & 0xffff0000u) * sc_g + sh_g;
      acc += fast_sigmoid(f0) * fast_softplus(g0);
      acc += fast_sigmoid(f1) * fast_softplus(g1);
      acc += fast_sigmoid(f2) * fast_softplus(g2);
      acc += fast_sigmoid(f3) * fast_softplus(g3);
    }
    for (; j < end; ++j) {
      unsigned p = __builtin_nontemporal_load(hbuf + (size_t)j * 64 + lane);
      float f = __uint_as_float(p << 16) * sc_f + sh_f;
      float g = __uint_as_float(p & 0xffff0000u) * sc_g + sh_g;
      acc += fast_sigmoid(f) * fast_softplus(g);
    }
    agg[(size_t)node * 64 + lane] = acc;
    ssum += acc; ssq += acc * acc;
  }
  __shared__ float red[4][64], redq[4][64];
  red[w][lane] = ssum; redq[w][lane] = ssq;
  __syncthreads();
  if (tid < 64) {
    unsafeAtomicAdd(&stats2[tid], red[0][tid] + red[1][tid] + red[2][tid] + red[3][tid]);
  } else if (tid < 128) {
    int t = tid - 64;
    unsafeAtomicAdd(&stats2[64 + t], redq[0][t] + redq[1][t] + redq[2][t] + redq[3][t]);
  }
}

// ---------------------------------------------------------------------------
// Kernel 4 (fallback, atomic): read packed h, BN1 affine, msg, scatter.
__global__ __launch_bounds__(256) void k_msg_scatter(
    const unsigned int* __restrict__ hbuf, const int* __restrict__ dst,
    const float* __restrict__ ss1, float* __restrict__ agg) {
  const int tid = threadIdx.x, lane = tid & 63, w = tid >> 6;
  const float sc_f = ss1[lane], sc_g = ss1[64 + lane];
  const float sh_f = ss1[128 + lane], sh_g = ss1[192 + lane];
  const int wave_id = blockIdx.x * 4 + w;
  const int n_waves = gridDim.x * 4;
  for (int e0 = wave_id * 8; e0 < N_EDGES; e0 += n_waves * 8) {
    unsigned int p[8];
    int d[8];
#pragma unroll
    for (int j = 0; j < 8; ++j) {
      p[j] = __builtin_nontemporal_load(hbuf + (size_t)(e0 + j) * 64 + lane);
      d[j] = __builtin_amdgcn_readfirstlane(dst[e0 + j]);
    }
#pragma unroll
    for (int j = 0; j < 8; ++j) {
      float f = __uint_as_float(p[j] << 16)          * sc_f + sh_f;
      float g = __uint_as_float(p[j] & 0xffff0000u)  * sc_g + sh_g;
      unsafeAtomicAdd(&agg[(size_t)d[j] * 64 + lane], fast_sigmoid(f) * fast_softplus(g));
    }
  }
}

// Fallback pass 2 (recompute h) if ws_size is too small for hbuf.
__global__ __launch_bounds__(256, 3) void k_edge_msg(
    const float* __restrict__ e_feat, const int* __restrict__ src,
    const int* __restrict__ dst, const float* __restrict__ W,
    const float* __restrict__ b, const unsigned* __restrict__ P1p,
    const unsigned* __restrict__ P2p, const float* __restrict__ ss1,
    float* __restrict__ agg) {
  const int tid = threadIdx.x, lane = tid & 63, w = tid >> 6;
  const int c = lane & 15;
  bf16x8 Bf[16];
  load_W3_frags(W, lane, Bf);
  float bn_[8], sc[8], sh[8];
#pragma unroll
  for (int nt = 0; nt < 8; ++nt) {
    bn_[nt] = b[nt * 16 + c];
    sc[nt]  = ss1[nt * 16 + c];
    sh[nt]  = ss1[128 + nt * 16 + c];
  }
  for (int g0 = blockIdx.x * 64; g0 < N_EDGES; g0 += gridDim.x * 64) {
    const int e0 = g0 + w * 16;
    float h[8][4]; int dIdx[4];
    compute_h(e0, lane, nullptr, e_feat, src, dst, P1p, P2p, bn_, Bf, h, dIdx);
#pragma unroll
    for (int nt = 0; nt < 4; ++nt) {
#pragma unroll
      for (int r = 0; r < 4; ++r) {
        float f = h[nt][r] * sc[nt] + sh[nt];
        float g = h[nt + 4][r] * sc[nt + 4] + sh[nt + 4];
        unsafeAtomicAdd(&agg[(size_t)dIdx[r] * 64 + nt * 16 + c],
                        fast_sigmoid(f) * fast_softplus(g));
      }
    }
  }
}

// Kernel 5: BN2 stats over agg rows (fallback paths only).
__global__ __launch_bounds__(256) void k_agg_stats(const float* __restrict__ agg,
                                                   float* __restrict__ stats2) {
  const int tid = threadIdx.x;
  const int c = tid & 63, w = tid >> 6;
  float s = 0.f, sq = 0.f;
  for (int r = blockIdx.x * 4 + w; r < N_NODES; r += gridDim.x * 4) {
    float v = agg[(size_t)r * 64 + c];
    s += v; sq += v * v;
  }
  __shared__ float ws_[4][64], wq_[4][64];
  ws_[w][c] = s; wq_[w][c] = sq;
  __syncthreads();
  if (tid < 64) {
    unsafeAtomicAdd(&stats2[tid], ws_[0][tid] + ws_[1][tid] + ws_[2][tid] + ws_[3][tid]);
  } else if (tid < 128) {
    int t = tid - 64;
    unsafeAtomicAdd(&stats2[64 + t], wq_[0][t] + wq_[1][t] + wq_[2][t] + wq_[3][t]);
  }
}

__global__ void k_finalize2(const float* __restrict__ stats2,
                            const float* __restrict__ g2,
                            const float* __restrict__ beta2,
                            float* __restrict__ ss2) {
  int t = threadIdx.x;
  if (t < 64) {
    float inv_n = 1.f / (float)N_NODES;
    float mu  = stats2[t] * inv_n;
    float var = stats2[64 + t] * inv_n - mu * mu;
    float sc  = g2[t] * rsqrtf(var + BN_EPS);
    ss2[t] = sc;
    ss2[64 + t] = beta2[t] - mu * sc;
  }
}

// Kernel 7: out = softplus(BN2(agg) + n_feat), float4-vectorized.
__global__ __launch_bounds__(256) void k_output(const float* __restrict__ agg,
                                                const float* __restrict__ n_feat,
                                                const float* __restrict__ ss2,
                                                float* __restrict__ out) {
  int i = blockIdx.x * 256 + threadIdx.x;
  if (i >= N_NODES * 16) return;
  int cb = (i & 15) * 4;
  float4 a = ((const float4*)agg)[i];
  float4 x = ((const float4*)n_feat)[i];
  float4 r;
  r.x = fast_softplus(a.x * ss2[cb + 0] + ss2[64 + cb + 0] + x.x);
  r.y = fast_softplus(a.y * ss2[cb + 1] + ss2[64 + cb + 1] + x.y);
  r.z = fast_softplus(a.z * ss2[cb + 2] + ss2[64 + cb + 2] + x.z);
  r.w = fast_softplus(a.w * ss2[cb + 3] + ss2[64 + cb + 3] + x.w);
  ((float4*)out)[i] = r;
}

extern "C" void kernel_launch(void* const* d_in, const int* in_sizes, int n_in,
                              void* d_out, int out_size, void* d_ws, size_t ws_size,
                              hipStream_t stream) {
  const float* n_feat = (const float*)d_in[0];
  const float* e_feat = (const float*)d_in[1];
  const int*   src    = (const int*)d_in[2];
  const int*   dst    = (const int*)d_in[3];
  const float* W      = (const float*)d_in[4];
  const float* b      = (const float*)d_in[5];
  const float* g1     = (const float*)d_in[6];
  const float* beta1  = (const float*)d_in[7];
  const float* g2     = (const float*)d_in[8];
  const float* beta2  = (const float*)d_in[9];

  unsigned* ws  = (unsigned*)d_ws;
  unsigned* P1p = ws;
  unsigned* P2p = ws + OFF_P2P;
  float* agg    = (float*)(ws + OFF_AGG);
  float* stats1 = (float*)(ws + OFF_STATS1);
  float* ss1    = stats1 + 256;
  float* stats2 = ss1 + 256;
  float* ss2    = stats2 + 128;
  unsigned int* hbuf = ws + OFF_HBUF;
  unsigned* perm   = ws + OFF_PERM;
  unsigned* offs   = ws + OFF_OFFS;
  unsigned* deg    = ws + OFF_DEG;
  unsigned* cursor = ws + OFF_CURS;
  unsigned* bsum   = ws + OFF_BSUM;
  float* out    = (float*)d_out;

  const bool have_hbuf = ws_size >= WS_WORDS_NEEDED * 4;
  const bool have_sort = ws_size >= WS_WORDS_SORTED * 4;

  hipMemsetAsync(stats1, 0, (256 + 256 + 128 + 128) * sizeof(float), stream);

  if (have_sort) {
    hipMemsetAsync(deg, 0, N_NODES * sizeof(unsigned), stream);
    // precompute P tables + fused dst histogram
    k_precompute<<<1024, 256, 0, stream>>>(n_feat, W, P1p, P2p, dst, deg);
    // hierarchical scan (multi-block; replaces the single-CU serial scan)
    k_scan1<<<NSCAN_BLOCKS, 256, 0, stream>>>(deg, bsum);
    k_scan2<<<NSCAN_BLOCKS, 256, 0, stream>>>(deg, bsum, offs, cursor);
    k_scatter_ids<<<(N_EDGES + 255) / 256, 256, 0, stream>>>(dst, cursor, perm);
    // edge pass in dst-sorted order -> hbuf contiguous per node
    k_edge_h<<<2048, 256, 0, stream>>>(e_feat, src, dst, W, b, P1p, P2p, perm,
                                       stats1, hbuf);
    k_finalize1<<<1, 128, 0, stream>>>(stats1, g1, beta1, ss1);
    // pure streaming gather: no perm, no atomics, fuses BN2 stats
    k_gather_msg<<<2048, 256, 0, stream>>>(hbuf, offs, ss1, agg, stats2);
  } else {
    hipMemsetAsync(agg, 0, (size_t)N_NODES * 64 * sizeof(float), stream);
    k_precompute<<<1024, 256, 0, stream>>>(n_feat, W, P1p, P2p, dst, nullptr);
    if (have_hbuf) {
      k_edge_h<<<2048, 256, 0, stream>>>(e_feat, src, dst, W, b, P1p, P2p,
                                         nullptr, stats1, hbuf);
      k_finalize1<<<1, 128, 0, stream>>>(stats1, g1, beta1, ss1);
      k_msg_scatter<<<2048, 256, 0, stream>>>(hbuf, dst, ss1, agg);
    } else {
      k_edge_h<<<2048, 256, 0, stream>>>(e_feat, src, dst, W, b, P1p, P2p,
                                         nullptr, stats1, nullptr);
      k_finalize1<<<1, 128, 0, stream>>>(stats1, g1, beta1, ss1);
      k_edge_msg<<<2048, 256, 0, stream>>>(e_feat, src, dst, W, b, P1p, P2p, ss1, agg);
    }
    k_agg_stats<<<512, 256, 0, stream>>>(agg, stats2);
  }
  k_finalize2<<<1, 64, 0, stream>>>(stats2, g2, beta2, ss2);
  k_output<<<3125, 256, 0, stream>>>(agg, n_feat, ss2, out);
}

// Round 4
// 644.179 us; speedup vs baseline: 1.2047x; 1.0280x over previous
//
#include <hip/hip_runtime.h>
#include <math.h>

// Problem constants (from reference)
#define N_NODES 50000
#define N_EDGES 800000
#define IN_DIM  192      // 2*O + ED
#define BN_EPS  1e-5f

// Workspace layout (4-byte word offsets):
//   P1p    [N,64]  uint @ 0          packed bf16x2 {chan n, chan n+64} of n_feat@W1^T
//   P2p    [N,64]  uint @ 3,200,000  same for W2^T
//   agg    [N,64]  f32  @ 6,400,000
//   stats1 [256]   f32  @ 9,600,000  (sum[128], sumsq[128])
//   ss1    [256]   f32  @ +256       (scale[128], shift[128])
//   stats2 [128]   f32  @ +512
//   ss2    [128]   f32  @ +640
//   hbuf   [E,64]  uint @ 9,601,024  packed bf16x2 {filt,core} per SORTED slot
//   perm   [E]     uint @ OFF_PERM   edge ids sorted by dst (counting sort)
//   offs   [N+1]   uint @ OFF_OFFS   CSR row offsets per dst node
//   deg    [N]     uint @ OFF_DEG    histogram scratch
//   cursor [N]     uint @ OFF_CURS   scatter cursors (copy of offs)
//   bsum   [256]   uint @ OFF_BSUM   per-block sums for hierarchical scan
#define OFF_P2P    3200000
#define OFF_AGG    6400000
#define OFF_STATS1 9600000
#define OFF_HBUF   9601024
#define WS_WORDS_NEEDED (OFF_HBUF + (size_t)N_EDGES * 64)
#define OFF_PERM   (OFF_HBUF + (size_t)N_EDGES * 64)
#define OFF_OFFS   (OFF_PERM + N_EDGES)
#define OFF_DEG    (OFF_OFFS + N_NODES + 1)
#define OFF_CURS   (OFF_DEG + N_NODES)
#define OFF_BSUM   (OFF_CURS + N_NODES)
#define WS_WORDS_SORTED (OFF_BSUM + 256)

#define NSCAN_BLOCKS 196   // ceil(50000/256)

typedef __bf16 bf16x8 __attribute__((ext_vector_type(8)));
typedef __bf16 bf16x2 __attribute__((ext_vector_type(2)));
typedef float  f32x4  __attribute__((ext_vector_type(4)));

__device__ __forceinline__ unsigned pack_bf16x2(float lo, float hi) {
  union { bf16x2 v; unsigned u; } pk;
  pk.v[0] = (__bf16)lo; pk.v[1] = (__bf16)hi;
  return pk.u;
}
// fast transcendentals (native v_exp/v_log/v_rcp)
__device__ __forceinline__ float fast_sigmoid(float f) {
  return __builtin_amdgcn_rcpf(1.f + __expf(-f));
}
__device__ __forceinline__ float fast_softplus(float g) {
  return fmaxf(g, 0.f) + __logf(1.f + __expf(-fabsf(g)));
}

// ---------------------------------------------------------------------------
// Kernel 1: P1p[n][o] = pack(bf16(n_feat[n]·W[o][0:64]), bf16(n_feat[n]·W[o+64][0:64]))
//           P2p same with k-range 64:128.
// Also (if deg != null) fused histogram of dst for the counting sort.
__global__ __launch_bounds__(256) void k_precompute(
    const float* __restrict__ n_feat, const float* __restrict__ W,
    unsigned* __restrict__ P1p, unsigned* __restrict__ P2p,
    const int* __restrict__ dst, unsigned* __restrict__ deg) {
  const int tid = threadIdx.x;
  if (deg) {
    for (int e = blockIdx.x * 256 + tid; e < N_EDGES; e += gridDim.x * 256)
      atomicAdd(&deg[dst[e]], 1u);
  }
  const int o   = tid & 63;
  const int sel = tid >> 6;                 // 0..3
  const int ch  = o + (sel & 1) * 64;
  const int kb  = (sel & 2) ? 64 : 0;
  float4 wreg[16];
  const float* wrow = W + (size_t)ch * IN_DIM + kb;
#pragma unroll
  for (int i = 0; i < 16; ++i) wreg[i] = *(const float4*)(wrow + i * 4);
  __shared__ float xrow[4][64];
  __shared__ float accbuf[4][4][64];        // [sel][r][o]
  for (int r0 = blockIdx.x * 4; r0 < N_NODES; r0 += gridDim.x * 4) {
    __syncthreads();
    xrow[tid >> 6][tid & 63] = n_feat[(size_t)(r0 + (tid >> 6)) * 64 + (tid & 63)];
    __syncthreads();
    float acc[4] = {0.f, 0.f, 0.f, 0.f};
#pragma unroll
    for (int kk = 0; kk < 16; ++kk) {
      float4 wv = wreg[kk];
#pragma unroll
      for (int r = 0; r < 4; ++r) {
        float4 xv = *(const float4*)&xrow[r][kk * 4];
        acc[r] += wv.x * xv.x + wv.y * xv.y + wv.z * xv.z + wv.w * xv.w;
      }
    }
#pragma unroll
    for (int r = 0; r < 4; ++r) accbuf[sel][r][o] = acc[r];
    __syncthreads();
    // thread (o, sel) packs+writes node row r0+sel
    const size_t rr = (size_t)(r0 + sel) * 64 + o;
    P1p[rr] = pack_bf16x2(accbuf[0][sel][o], accbuf[1][sel][o]);
    P2p[rr] = pack_bf16x2(accbuf[2][sel][o], accbuf[3][sel][o]);
  }
}

// ---------------------------------------------------------------------------
// Hierarchical exclusive scan of deg[N_NODES] -> offs/cursor.
// scan1: per-block (256 elems) sums.
__global__ __launch_bounds__(256) void k_scan1(const unsigned* __restrict__ deg,
                                               unsigned* __restrict__ bsum) {
  const int t = threadIdx.x;
  const int i = blockIdx.x * 256 + t;
  __shared__ unsigned r[256];
  r[t] = (i < N_NODES) ? deg[i] : 0u;
  __syncthreads();
  for (int off = 128; off > 0; off >>= 1) {
    if (t < off) r[t] += r[t + off];
    __syncthreads();
  }
  if (t == 0) bsum[blockIdx.x] = r[0];
}

// scan2: each block redundantly scans bsum[196] (cheap), then local scan.
__global__ __launch_bounds__(256) void k_scan2(const unsigned* __restrict__ deg,
                                               const unsigned* __restrict__ bsum,
                                               unsigned* __restrict__ offs,
                                               unsigned* __restrict__ cursor) {
  const int t = threadIdx.x;
  __shared__ unsigned sb[256];
  sb[t] = (t < NSCAN_BLOCKS) ? bsum[t] : 0u;
  __syncthreads();
  for (int off = 1; off < 256; off <<= 1) {
    unsigned add = (t >= off) ? sb[t - off] : 0u;
    __syncthreads();
    sb[t] += add;
    __syncthreads();
  }
  const unsigned base = (blockIdx.x == 0) ? 0u : sb[blockIdx.x - 1];
  const int i = blockIdx.x * 256 + t;
  const unsigned v = (i < N_NODES) ? deg[i] : 0u;
  __shared__ unsigned sd[256];
  sd[t] = v;
  __syncthreads();
  for (int off = 1; off < 256; off <<= 1) {
    unsigned add = (t >= off) ? sd[t - off] : 0u;
    __syncthreads();
    sd[t] += add;
    __syncthreads();
  }
  const unsigned excl = base + sd[t] - v;
  if (i < N_NODES) { offs[i] = excl; cursor[i] = excl; }
  if (blockIdx.x == 0 && t == 0) offs[N_NODES] = N_EDGES;
}

__global__ __launch_bounds__(256) void k_scatter_ids(
    const int* __restrict__ dst, unsigned* __restrict__ cursor,
    unsigned* __restrict__ perm) {
  int e = blockIdx.x * 256 + threadIdx.x;
  if (e < N_EDGES) {
    unsigned pos = atomicAdd(&cursor[dst[e]], 1u);
    perm[pos] = e;
  }
}

// ---------------------------------------------------------------------------
// W3 fragment loader shared by edge kernels.
//   D-frag: lane holds D[m=(lane>>4)*4+r][n=nt*16+(lane&15)]
__device__ __forceinline__ void load_W3_frags(const float* __restrict__ W,
                                              int lane, bf16x8* Bf) {
  const int c = lane & 15, q = lane >> 4;
#pragma unroll
  for (int nt = 0; nt < 8; ++nt) {
#pragma unroll
    for (int ks = 0; ks < 2; ++ks) {
      const float* wr = W + (size_t)(nt * 16 + c) * IN_DIM + 128 + ks * 32 + q * 8;
      f32x4 w0 = *(const f32x4*)wr;
      f32x4 w1 = *(const f32x4*)(wr + 4);
      bf16x8 f;
#pragma unroll
      for (int j = 0; j < 4; ++j) { f[j] = (__bf16)w0[j]; f[4 + j] = (__bf16)w1[j]; }
      Bf[nt * 2 + ks] = f;
    }
  }
}

// Fallback (unsorted) edge-pass core: wave computes h[16 edges][128 ch].
__device__ __forceinline__ void compute_h(
    int e0, int lane, const float* __restrict__ e_feat,
    const int* __restrict__ src, const int* __restrict__ dst,
    const unsigned* __restrict__ P1p, const unsigned* __restrict__ P2p,
    const float* __restrict__ bn_, const bf16x8* Bf,
    float h[8][4], int dIdx[4]) {
  const int c = lane & 15, q = lane >> 4;
  const float* er = e_feat + (size_t)(e0 + c) * 64 + q * 8;
  f32x4 a0 = __builtin_nontemporal_load((const f32x4*)er);
  f32x4 a1 = __builtin_nontemporal_load((const f32x4*)(er + 4));
  f32x4 a2 = __builtin_nontemporal_load((const f32x4*)(er + 32));
  f32x4 a3 = __builtin_nontemporal_load((const f32x4*)(er + 36));
  int sIdx[4];
#pragma unroll
  for (int r = 0; r < 4; ++r) {
    dIdx[r] = dst[e0 + q * 4 + r];
    sIdx[r] = src[e0 + q * 4 + r];
  }
  bf16x8 A0, A1;
#pragma unroll
  for (int j = 0; j < 4; ++j) {
    A0[j] = (__bf16)a0[j]; A0[4 + j] = (__bf16)a1[j];
    A1[j] = (__bf16)a2[j]; A1[4 + j] = (__bf16)a3[j];
  }
  f32x4 acc[8];
#pragma unroll
  for (int nt = 0; nt < 8; ++nt) {
    acc[nt] = (f32x4){0.f, 0.f, 0.f, 0.f};
    acc[nt] = __builtin_amdgcn_mfma_f32_16x16x32_bf16(A0, Bf[nt * 2 + 0], acc[nt], 0, 0, 0);
    acc[nt] = __builtin_amdgcn_mfma_f32_16x16x32_bf16(A1, Bf[nt * 2 + 1], acc[nt], 0, 0, 0);
  }
#pragma unroll
  for (int r = 0; r < 4; ++r) {
    const unsigned* p1r = P1p + (size_t)dIdx[r] * 64 + c;
    const unsigned* p2r = P2p + (size_t)sIdx[r] * 64 + c;
#pragma unroll
    for (int ntp = 0; ntp < 4; ++ntp) {
      unsigned u1 = p1r[ntp * 16];
      unsigned u2 = p2r[ntp * 16];
      float lo = __uint_as_float(u1 << 16) + __uint_as_float(u2 << 16);
      float hi = __uint_as_float(u1 & 0xffff0000u) + __uint_as_float(u2 & 0xffff0000u);
      h[ntp][r]     = acc[ntp][r]     + lo + bn_[ntp];
      h[ntp + 4][r] = acc[ntp + 4][r] + hi + bn_[ntp + 4];
    }
  }
}

// ---------------------------------------------------------------------------
// Kernel 2 (sorted): slot-order edge pass with 2-deep index software pipeline.
//   Index chain per tile is {perm -> dst/src} but prefetched across
//   iterations so every load's address is ready at iteration entry.
//   dIdx/sIdx distributed to r-slots via __shfl (16 broadcast values).
//   hbuf stores are CACHED (not nontemporal) so the following streaming
//   gather can hit L3 instead of HBM.
__global__ __launch_bounds__(256, 3) void k_edge_h_sorted(
    const float* __restrict__ e_feat, const int* __restrict__ src,
    const int* __restrict__ dst, const unsigned* __restrict__ perm,
    const float* __restrict__ W, const float* __restrict__ b,
    const unsigned* __restrict__ P1p, const unsigned* __restrict__ P2p,
    float* __restrict__ stats1, unsigned int* __restrict__ hbuf) {
  const int tid = threadIdx.x, lane = tid & 63, w = tid >> 6;
  const int c = lane & 15, q = lane >> 4;
  bf16x8 Bf[16];
  load_W3_frags(W, lane, Bf);
  float bn_[8];
#pragma unroll
  for (int nt = 0; nt < 8; ++nt) bn_[nt] = b[nt * 16 + c];
  float sums[8] = {0, 0, 0, 0, 0, 0, 0, 0};
  float sqs[8]  = {0, 0, 0, 0, 0, 0, 0, 0};

  const int stride = gridDim.x * 64;
  int e0 = blockIdx.x * 64 + w * 16;

  // pipeline prologue: pv for tiles 0 and 1, dv/sv for tile 0
  unsigned pv0 = 0, dv0 = 0, sv0 = 0, pv1 = 0;
  if (e0 < N_EDGES) {
    pv0 = perm[e0 + c];
    dv0 = (unsigned)dst[pv0];
    sv0 = (unsigned)src[pv0];
    if (e0 + stride < N_EDGES) pv1 = perm[e0 + stride + c];
  }

  for (; e0 < N_EDGES; e0 += stride) {
    const int e1 = e0 + stride, e2 = e0 + 2 * stride;
    // current tile e_feat (addresses ready: pv0 from last iteration)
    const float* er = e_feat + (size_t)pv0 * 64 + q * 8;
    f32x4 a0 = __builtin_nontemporal_load((const f32x4*)er);
    f32x4 a1 = __builtin_nontemporal_load((const f32x4*)(er + 4));
    f32x4 a2 = __builtin_nontemporal_load((const f32x4*)(er + 32));
    f32x4 a3 = __builtin_nontemporal_load((const f32x4*)(er + 36));
    // prefetch: dv/sv for tile+1 (pv1 ready), pv for tile+2
    unsigned dv1 = 0, sv1 = 0, pv2 = 0;
    if (e1 < N_EDGES) { dv1 = (unsigned)dst[pv1]; sv1 = (unsigned)src[pv1]; }
    if (e2 < N_EDGES) pv2 = perm[e2 + c];
    // distribute current indices to r-slots (broadcast from lanes 0..15)
    int dIdx[4], sIdx[4];
#pragma unroll
    for (int r = 0; r < 4; ++r) {
      dIdx[r] = __shfl((int)dv0, q * 4 + r, 64);
      sIdx[r] = __shfl((int)sv0, q * 4 + r, 64);
    }
    // MFMA
    bf16x8 A0, A1;
#pragma unroll
    for (int j = 0; j < 4; ++j) {
      A0[j] = (__bf16)a0[j]; A0[4 + j] = (__bf16)a1[j];
      A1[j] = (__bf16)a2[j]; A1[4 + j] = (__bf16)a3[j];
    }
    f32x4 acc[8];
#pragma unroll
    for (int nt = 0; nt < 8; ++nt) {
      acc[nt] = (f32x4){0.f, 0.f, 0.f, 0.f};
      acc[nt] = __builtin_amdgcn_mfma_f32_16x16x32_bf16(A0, Bf[nt * 2 + 0], acc[nt], 0, 0, 0);
      acc[nt] = __builtin_amdgcn_mfma_f32_16x16x32_bf16(A1, Bf[nt * 2 + 1], acc[nt], 0, 0, 0);
    }
    // P gathers (dst-sorted -> dIdx nearly uniform per tile, L1/L2-hot)
    float h[8][4];
#pragma unroll
    for (int r = 0; r < 4; ++r) {
      const unsigned* p1r = P1p + (size_t)dIdx[r] * 64 + c;
      const unsigned* p2r = P2p + (size_t)sIdx[r] * 64 + c;
#pragma unroll
      for (int ntp = 0; ntp < 4; ++ntp) {
        unsigned u1 = p1r[ntp * 16];
        unsigned u2 = p2r[ntp * 16];
        float lo = __uint_as_float(u1 << 16) + __uint_as_float(u2 << 16);
        float hi = __uint_as_float(u1 & 0xffff0000u) + __uint_as_float(u2 & 0xffff0000u);
        h[ntp][r]     = acc[ntp][r]     + lo + bn_[ntp];
        h[ntp + 4][r] = acc[ntp + 4][r] + hi + bn_[ntp + 4];
      }
    }
    // BN1 stats + cached hbuf store
#pragma unroll
    for (int nt = 0; nt < 8; ++nt)
#pragma unroll
      for (int r = 0; r < 4; ++r) {
        sums[nt] += h[nt][r];
        sqs[nt]  += h[nt][r] * h[nt][r];
      }
#pragma unroll
    for (int r = 0; r < 4; ++r) {
      unsigned int* hb = hbuf + (size_t)(e0 + q * 4 + r) * 64 + c;
#pragma unroll
      for (int nt = 0; nt < 4; ++nt)
        hb[nt * 16] = pack_bf16x2(h[nt][r], h[nt + 4][r]);
    }
    // rotate pipeline
    pv0 = pv1; dv0 = dv1; sv0 = sv1; pv1 = pv2;
  }

  __shared__ float red[4][256];
#pragma unroll
  for (int nt = 0; nt < 8; ++nt) {
    float s = sums[nt]; s += __shfl_xor(s, 16, 64); s += __shfl_xor(s, 32, 64);
    float qv = sqs[nt]; qv += __shfl_xor(qv, 16, 64); qv += __shfl_xor(qv, 32, 64);
    if (lane < 16) { red[w][nt * 16 + lane] = s; red[w][128 + nt * 16 + lane] = qv; }
  }
  __syncthreads();
  float v = red[0][tid] + red[1][tid] + red[2][tid] + red[3][tid];
  unsafeAtomicAdd(&stats1[tid], v);
}

// Kernel 2 (fallback, unsorted order): compute h, stats, optional hbuf store.
__global__ __launch_bounds__(256, 3) void k_edge_h(
    const float* __restrict__ e_feat, const int* __restrict__ src,
    const int* __restrict__ dst, const float* __restrict__ W,
    const float* __restrict__ b, const unsigned* __restrict__ P1p,
    const unsigned* __restrict__ P2p, float* __restrict__ stats1,
    unsigned int* __restrict__ hbuf) {
  const int tid = threadIdx.x, lane = tid & 63, w = tid >> 6;
  const int c = lane & 15, q = lane >> 4;
  bf16x8 Bf[16];
  load_W3_frags(W, lane, Bf);
  float bn_[8];
#pragma unroll
  for (int nt = 0; nt < 8; ++nt) bn_[nt] = b[nt * 16 + c];
  float sums[8] = {0, 0, 0, 0, 0, 0, 0, 0};
  float sqs[8]  = {0, 0, 0, 0, 0, 0, 0, 0};
  for (int g0 = blockIdx.x * 64; g0 < N_EDGES; g0 += gridDim.x * 64) {
    const int e0 = g0 + w * 16;
    float h[8][4]; int dIdx[4];
    compute_h(e0, lane, e_feat, src, dst, P1p, P2p, bn_, Bf, h, dIdx);
#pragma unroll
    for (int nt = 0; nt < 8; ++nt)
#pragma unroll
      for (int r = 0; r < 4; ++r) {
        sums[nt] += h[nt][r];
        sqs[nt]  += h[nt][r] * h[nt][r];
      }
    if (hbuf) {
#pragma unroll
      for (int r = 0; r < 4; ++r) {
        unsigned int* hb = hbuf + (size_t)(e0 + q * 4 + r) * 64 + c;
#pragma unroll
        for (int nt = 0; nt < 4; ++nt)
          hb[nt * 16] = pack_bf16x2(h[nt][r], h[nt + 4][r]);
      }
    }
  }
  __shared__ float red[4][256];
#pragma unroll
  for (int nt = 0; nt < 8; ++nt) {
    float s = sums[nt]; s += __shfl_xor(s, 16, 64); s += __shfl_xor(s, 32, 64);
    float qv = sqs[nt]; qv += __shfl_xor(qv, 16, 64); qv += __shfl_xor(qv, 32, 64);
    if (lane < 16) { red[w][nt * 16 + lane] = s; red[w][128 + nt * 16 + lane] = qv; }
  }
  __syncthreads();
  float v = red[0][tid] + red[1][tid] + red[2][tid] + red[3][tid];
  unsafeAtomicAdd(&stats1[tid], v);
}

// Kernel 3: fold BN1 into per-channel affine.
__global__ void k_finalize1(const float* __restrict__ stats1,
                            const float* __restrict__ g1,
                            const float* __restrict__ beta1,
                            float* __restrict__ ss1) {
  int t = threadIdx.x;
  if (t < 128) {
    float inv_n = 1.f / (float)N_EDGES;
    float mu  = stats1[t] * inv_n;
    float var = stats1[128 + t] * inv_n - mu * mu;
    float sc  = g1[t] * rsqrtf(var + BN_EPS);
    ss1[t] = sc;
    ss1[128 + t] = beta1[t] - mu * sc;
  }
}

__device__ __forceinline__ float msg_of(unsigned p, float sc_f, float sh_f,
                                        float sc_g, float sh_g) {
  float f = __uint_as_float(p << 16) * sc_f + sh_f;
  float g = __uint_as_float(p & 0xffff0000u) * sc_g + sh_g;
  return fast_sigmoid(f) * fast_softplus(g);
}

// ---------------------------------------------------------------------------
// Kernel 4 (sorted): hbuf is in dst-sorted slot order, so node n owns the
// contiguous slot range [offs[n], offs[n+1]).  Streaming CACHED reads (hbuf
// lines are L3-resident from the cached edge-pass stores), BN1 affine,
// msg=sigmoid*softplus, register-accumulate, single agg write.
// Fuses BN2 stats (no k_agg_stats, no agg memset, zero atomics on agg).
__global__ __launch_bounds__(256) void k_gather_msg(
    const unsigned int* __restrict__ hbuf, const unsigned* __restrict__ offs,
    const float* __restrict__ ss1, float* __restrict__ agg,
    float* __restrict__ stats2) {
  const int tid = threadIdx.x, lane = tid & 63, w = tid >> 6;
  const float sc_f = ss1[lane], sc_g = ss1[64 + lane];
  const float sh_f = ss1[128 + lane], sh_g = ss1[192 + lane];
  const int wave_id = blockIdx.x * 4 + w;
  const int n_waves = gridDim.x * 4;
  float ssum = 0.f, ssq = 0.f;
  for (int node = wave_id; node < N_NODES; node += n_waves) {
    const int start = (int)offs[node], end = (int)offs[node + 1];
    float acc = 0.f;
    int j = start;
    for (; j + 8 <= end; j += 8) {
      unsigned p[8];
#pragma unroll
      for (int k = 0; k < 8; ++k) p[k] = hbuf[(size_t)(j + k) * 64 + lane];
#pragma unroll
      for (int k = 0; k < 8; ++k) acc += msg_of(p[k], sc_f, sh_f, sc_g, sh_g);
    }
    for (; j < end; ++j)
      acc += msg_of(hbuf[(size_t)j * 64 + lane], sc_f, sh_f, sc_g, sh_g);
    agg[(size_t)node * 64 + lane] = acc;
    ssum += acc; ssq += acc * acc;
  }
  __shared__ float red[4][64], redq[4][64];
  red[w][lane] = ssum; redq[w][lane] = ssq;
  __syncthreads();
  if (tid < 64) {
    unsafeAtomicAdd(&stats2[tid], red[0][tid] + red[1][tid] + red[2][tid] + red[3][tid]);
  } else if (tid < 128) {
    int t = tid - 64;
    unsafeAtomicAdd(&stats2[64 + t], redq[0][t] + redq[1][t] + redq[2][t] + redq[3][t]);
  }
}

// ---------------------------------------------------------------------------
// Kernel 4 (fallback, atomic): read packed h, BN1 affine, msg, scatter.
__global__ __launch_bounds__(256) void k_msg_scatter(
    const unsigned int* __restrict__ hbuf, const int* __restrict__ dst,
    const float* __restrict__ ss1, float* __restrict__ agg) {
  const int tid = threadIdx.x, lane = tid & 63, w = tid >> 6;
  const float sc_f = ss1[lane], sc_g = ss1[64 + lane];
  const float sh_f = ss1[128 + lane], sh_g = ss1[192 + lane];
  const int wave_id = blockIdx.x * 4 + w;
  const int n_waves = gridDim.x * 4;
  for (int e0 = wave_id * 8; e0 < N_EDGES; e0 += n_waves * 8) {
    unsigned int p[8];
    int d[8];
#pragma unroll
    for (int j = 0; j < 8; ++j) {
      p[j] = hbuf[(size_t)(e0 + j) * 64 + lane];
      d[j] = __builtin_amdgcn_readfirstlane(dst[e0 + j]);
    }
#pragma unroll
    for (int j = 0; j < 8; ++j) {
      unsafeAtomicAdd(&agg[(size_t)d[j] * 64 + lane],
                      msg_of(p[j], sc_f, sh_f, sc_g, sh_g));
    }
  }
}

// Fallback pass 2 (recompute h) if ws_size is too small for hbuf.
__global__ __launch_bounds__(256, 3) void k_edge_msg(
    const float* __restrict__ e_feat, const int* __restrict__ src,
    const int* __restrict__ dst, const float* __restrict__ W,
    const float* __restrict__ b, const unsigned* __restrict__ P1p,
    const unsigned* __restrict__ P2p, const float* __restrict__ ss1,
    float* __restrict__ agg) {
  const int tid = threadIdx.x, lane = tid & 63, w = tid >> 6;
  const int c = lane & 15;
  bf16x8 Bf[16];
  load_W3_frags(W, lane, Bf);
  float bn_[8], sc[8], sh[8];
#pragma unroll
  for (int nt = 0; nt < 8; ++nt) {
    bn_[nt] = b[nt * 16 + c];
    sc[nt]  = ss1[nt * 16 + c];
    sh[nt]  = ss1[128 + nt * 16 + c];
  }
  for (int g0 = blockIdx.x * 64; g0 < N_EDGES; g0 += gridDim.x * 64) {
    const int e0 = g0 + w * 16;
    float h[8][4]; int dIdx[4];
    compute_h(e0, lane, e_feat, src, dst, P1p, P2p, bn_, Bf, h, dIdx);
#pragma unroll
    for (int nt = 0; nt < 4; ++nt) {
#pragma unroll
      for (int r = 0; r < 4; ++r) {
        float f = h[nt][r] * sc[nt] + sh[nt];
        float g = h[nt + 4][r] * sc[nt + 4] + sh[nt + 4];
        unsafeAtomicAdd(&agg[(size_t)dIdx[r] * 64 + nt * 16 + c],
                        fast_sigmoid(f) * fast_softplus(g));
      }
    }
  }
}

// Kernel 5: BN2 stats over agg rows (fallback paths only).
__global__ __launch_bounds__(256) void k_agg_stats(const float* __restrict__ agg,
                                                   float* __restrict__ stats2) {
  const int tid = threadIdx.x;
  const int c = tid & 63, w = tid >> 6;
  float s = 0.f, sq = 0.f;
  for (int r = blockIdx.x * 4 + w; r < N_NODES; r += gridDim.x * 4) {
    float v = agg[(size_t)r * 64 + c];
    s += v; sq += v * v;
  }
  __shared__ float ws_[4][64], wq_[4][64];
  ws_[w][c] = s; wq_[w][c] = sq;
  __syncthreads();
  if (tid < 64) {
    unsafeAtomicAdd(&stats2[tid], ws_[0][tid] + ws_[1][tid] + ws_[2][tid] + ws_[3][tid]);
  } else if (tid < 128) {
    int t = tid - 64;
    unsafeAtomicAdd(&stats2[64 + t], wq_[0][t] + wq_[1][t] + wq_[2][t] + wq_[3][t]);
  }
}

__global__ void k_finalize2(const float* __restrict__ stats2,
                            const float* __restrict__ g2,
                            const float* __restrict__ beta2,
                            float* __restrict__ ss2) {
  int t = threadIdx.x;
  if (t < 64) {
    float inv_n = 1.f / (float)N_NODES;
    float mu  = stats2[t] * inv_n;
    float var = stats2[64 + t] * inv_n - mu * mu;
    float sc  = g2[t] * rsqrtf(var + BN_EPS);
    ss2[t] = sc;
    ss2[64 + t] = beta2[t] - mu * sc;
  }
}

// Kernel 7: out = softplus(BN2(agg) + n_feat), float4-vectorized.
__global__ __launch_bounds__(256) void k_output(const float* __restrict__ agg,
                                                const float* __restrict__ n_feat,
                                                const float* __restrict__ ss2,
                                                float* __restrict__ out) {
  int i = blockIdx.x * 256 + threadIdx.x;
  if (i >= N_NODES * 16) return;
  int cb = (i & 15) * 4;
  float4 a = ((const float4*)agg)[i];
  float4 x = ((const float4*)n_feat)[i];
  float4 r;
  r.x = fast_softplus(a.x * ss2[cb + 0] + ss2[64 + cb + 0] + x.x);
  r.y = fast_softplus(a.y * ss2[cb + 1] + ss2[64 + cb + 1] + x.y);
  r.z = fast_softplus(a.z * ss2[cb + 2] + ss2[64 + cb + 2] + x.z);
  r.w = fast_softplus(a.w * ss2[cb + 3] + ss2[64 + cb + 3] + x.w);
  ((float4*)out)[i] = r;
}

extern "C" void kernel_launch(void* const* d_in, const int* in_sizes, int n_in,
                              void* d_out, int out_size, void* d_ws, size_t ws_size,
                              hipStream_t stream) {
  const float* n_feat = (const float*)d_in[0];
  const float* e_feat = (const float*)d_in[1];
  const int*   src    = (const int*)d_in[2];
  const int*   dst    = (const int*)d_in[3];
  const float* W      = (const float*)d_in[4];
  const float* b      = (const float*)d_in[5];
  const float* g1     = (const float*)d_in[6];
  const float* beta1  = (const float*)d_in[7];
  const float* g2     = (const float*)d_in[8];
  const float* beta2  = (const float*)d_in[9];

  unsigned* ws  = (unsigned*)d_ws;
  unsigned* P1p = ws;
  unsigned* P2p = ws + OFF_P2P;
  float* agg    = (float*)(ws + OFF_AGG);
  float* stats1 = (float*)(ws + OFF_STATS1);
  float* ss1    = stats1 + 256;
  float* stats2 = ss1 + 256;
  float* ss2    = stats2 + 128;
  unsigned int* hbuf = ws + OFF_HBUF;
  unsigned* perm   = ws + OFF_PERM;
  unsigned* offs   = ws + OFF_OFFS;
  unsigned* deg    = ws + OFF_DEG;
  unsigned* cursor = ws + OFF_CURS;
  unsigned* bsum   = ws + OFF_BSUM;
  float* out    = (float*)d_out;

  const bool have_hbuf = ws_size >= WS_WORDS_NEEDED * 4;
  const bool have_sort = ws_size >= WS_WORDS_SORTED * 4;

  hipMemsetAsync(stats1, 0, (256 + 256 + 128 + 128) * sizeof(float), stream);

  if (have_sort) {
    hipMemsetAsync(deg, 0, N_NODES * sizeof(unsigned), stream);
    // precompute P tables + fused dst histogram
    k_precompute<<<1024, 256, 0, stream>>>(n_feat, W, P1p, P2p, dst, deg);
    // hierarchical scan
    k_scan1<<<NSCAN_BLOCKS, 256, 0, stream>>>(deg, bsum);
    k_scan2<<<NSCAN_BLOCKS, 256, 0, stream>>>(deg, bsum, offs, cursor);
    k_scatter_ids<<<(N_EDGES + 255) / 256, 256, 0, stream>>>(dst, cursor, perm);
    // edge pass in dst-sorted order, software-pipelined indices
    k_edge_h_sorted<<<2048, 256, 0, stream>>>(e_feat, src, dst, perm, W, b,
                                              P1p, P2p, stats1, hbuf);
    k_finalize1<<<1, 128, 0, stream>>>(stats1, g1, beta1, ss1);
    // pure streaming gather: no perm, no atomics, fuses BN2 stats
    k_gather_msg<<<2048, 256, 0, stream>>>(hbuf, offs, ss1, agg, stats2);
  } else {
    hipMemsetAsync(agg, 0, (size_t)N_NODES * 64 * sizeof(float), stream);
    k_precompute<<<1024, 256, 0, stream>>>(n_feat, W, P1p, P2p, dst, nullptr);
    if (have_hbuf) {
      k_edge_h<<<2048, 256, 0, stream>>>(e_feat, src, dst, W, b, P1p, P2p,
                                         stats1, hbuf);
      k_finalize1<<<1, 128, 0, stream>>>(stats1, g1, beta1, ss1);
      k_msg_scatter<<<2048, 256, 0, stream>>>(hbuf, dst, ss1, agg);
    } else {
      k_edge_h<<<2048, 256, 0, stream>>>(e_feat, src, dst, W, b, P1p, P2p,
                                         stats1, nullptr);
      k_finalize1<<<1, 128, 0, stream>>>(stats1, g1, beta1, ss1);
      k_edge_msg<<<2048, 256, 0, stream>>>(e_feat, src, dst, W, b, P1p, P2p, ss1, agg);
    }
    k_agg_stats<<<512, 256, 0, stream>>>(agg, stats2);
  }
  k_finalize2<<<1, 64, 0, stream>>>(stats2, g2, beta2, ss2);
  k_output<<<3125, 256, 0, stream>>>(agg, n_feat, ss2, out);
}